// Round 1
// baseline (2222.278 us; speedup 1.0000x reference)
//
#include <hip/hip_runtime.h>
#include <math.h>

#define G    32
#define N    2048
#define IND  128
#define LD   64
#define KSUB 64
#define NN   ((size_t)N*(size_t)N)

__device__ __forceinline__ float eluf(float x){ return x > 0.f ? x : expm1f(x); }

__device__ __forceinline__ float waveReduceSum(float v){
  #pragma unroll
  for (int o = 32; o > 0; o >>= 1) v += __shfl_xor(v, o, 64);
  return v;
}

// ---------- 1) row degrees -> reciprocal ----------
__global__ void k_deg(const float* __restrict__ g, float* __restrict__ rdeg){
  int wave = threadIdx.x >> 6, lane = threadIdx.x & 63;
  int row = blockIdx.x * 4 + wave;              // 0 .. G*N-1
  const float* gr = g + (size_t)row * N;
  float s = 0.f;
  #pragma unroll
  for (int it = 0; it < 8; ++it){
    float4 v = *(const float4*)(gr + it*256 + lane*4);
    s += v.x + v.y + v.z + v.w;
  }
  s = waveReduceSum(s);
  if (lane == 0) rdeg[row] = 1.0f / s;
}

// ---------- 2) xwn[g,j,c] = (x[g,j,:] @ W)[c] * rdeg[g,j] ----------
__global__ void k_xw(const float* __restrict__ x, const float* __restrict__ Wg,
                     const float* __restrict__ rdeg, float* __restrict__ xwn){
  int gi = blockIdx.x;
  int row = blockIdx.y * 256 + threadIdx.x;
  const float* xr = x + ((size_t)gi*N + row) * IND;
  float acc[LD];
  #pragma unroll
  for (int c = 0; c < LD; ++c) acc[c] = 0.f;
  for (int k8 = 0; k8 < IND; k8 += 8){
    float ka[8];
    *(float4*)&ka[0] = *(const float4*)(xr + k8);
    *(float4*)&ka[4] = *(const float4*)(xr + k8 + 4);
    #pragma unroll
    for (int kk = 0; kk < 8; ++kk){
      const float* Bk = Wg + (k8+kk)*LD;            // wave-uniform -> s_load
      #pragma unroll
      for (int c = 0; c < LD; ++c) acc[c] = fmaf(ka[kk], Bk[c], acc[c]);
    }
  }
  float rd = rdeg[gi*N + row];
  float* o = xwn + ((size_t)gi*N + row) * LD;
  #pragma unroll
  for (int c4 = 0; c4 < LD; c4 += 4){
    float4 v; v.x=acc[c4]*rd; v.y=acc[c4+1]*rd; v.z=acc[c4+2]*rd; v.w=acc[c4+3]*rd;
    *(float4*)(o + c4) = v;
  }
}

// ---------- 3) hn = elu(g @ xwn + b); accumulate LN stats ----------
__global__ void k_mm(const float* __restrict__ g, const float* __restrict__ xwn,
                     const float* __restrict__ bgcn, float* __restrict__ hn,
                     float* __restrict__ stats){
  int gi = blockIdx.x;
  int row = blockIdx.y * 256 + threadIdx.x;
  const float* ar = g + (size_t)gi*NN + (size_t)row*N;
  const float* B  = xwn + (size_t)gi*N*LD;
  float acc[LD];
  #pragma unroll
  for (int c = 0; c < LD; ++c) acc[c] = 0.f;
  float4 p0 = *(const float4*)(ar);
  float4 p1 = *(const float4*)(ar + 4);
  for (int k8 = 0; k8 < N; k8 += 8){
    float ka[8];
    *(float4*)&ka[0] = p0; *(float4*)&ka[4] = p1;
    if (k8 + 8 < N){                                // prefetch next
      p0 = *(const float4*)(ar + k8 + 8);
      p1 = *(const float4*)(ar + k8 + 12);
    }
    #pragma unroll
    for (int kk = 0; kk < 8; ++kk){
      const float* Bk = B + (size_t)(k8+kk)*LD;     // wave-uniform -> s_load
      #pragma unroll
      for (int c = 0; c < LD; ++c) acc[c] = fmaf(ka[kk], Bk[c], acc[c]);
    }
  }
  float s1 = 0.f, s2 = 0.f;
  float* o = hn + ((size_t)gi*N + row)*LD;
  #pragma unroll
  for (int c4 = 0; c4 < LD; c4 += 4){
    float4 v;
    v.x = eluf(acc[c4+0] + bgcn[c4+0]);
    v.y = eluf(acc[c4+1] + bgcn[c4+1]);
    v.z = eluf(acc[c4+2] + bgcn[c4+2]);
    v.w = eluf(acc[c4+3] + bgcn[c4+3]);
    s1 += v.x+v.y+v.z+v.w;
    s2 += v.x*v.x + v.y*v.y + v.z*v.z + v.w*v.w;
    *(float4*)(o + c4) = v;
  }
  s1 = waveReduceSum(s1); s2 = waveReduceSum(s2);
  __shared__ float red[8];
  int wave = threadIdx.x>>6, lane = threadIdx.x&63;
  if (lane==0){ red[wave]=s1; red[4+wave]=s2; }
  __syncthreads();
  if (threadIdx.x==0){
    atomicAdd(&stats[gi*2+0], red[0]+red[1]+red[2]+red[3]);
    atomicAdd(&stats[gi*2+1], red[4]+red[5]+red[6]+red[7]);
  }
}

// ---------- 4) finalize LN stats ----------
__global__ void k_stats(const float* __restrict__ stats, float* __restrict__ mu,
                        float* __restrict__ rs){
  int t = threadIdx.x;
  if (t < G){
    const float inv = 1.0f/(float)(N*LD);
    float m = stats[2*t]*inv;
    float v = stats[2*t+1]*inv - m*m;
    mu[t] = m; rs[t] = rsqrtf(v + 1e-5f);
  }
}

// ---------- 5) normalize in-place, scores, column sums ----------
__global__ void k_score(float* __restrict__ hn, const float* __restrict__ p,
                        const float* __restrict__ muA, const float* __restrict__ rsA,
                        float* __restrict__ scores, float* __restrict__ colsum){
  int gi = blockIdx.x;
  int wave = threadIdx.x>>6, lane = threadIdx.x&63;
  int rbase = blockIdx.y*256 + wave*64;
  float mu = muA[gi], rs = rsA[gi], pl = p[lane];
  float cs = 0.f;
  for (int r = 0; r < 64; ++r){
    int row = rbase + r;
    float* hp = hn + ((size_t)gi*N + row)*LD + lane;
    float v = (*hp - mu) * rs;
    *hp = v;
    cs += v;
    float sv = waveReduceSum(v * pl);
    if (lane == 0) scores[gi*N + row] = sv;
  }
  atomicAdd(&colsum[gi*LD + lane], cs);
}

// ---------- 6) exact top-64 (desc value, asc index on ties) ----------
__global__ void k_topk(const float* __restrict__ scores, int* __restrict__ idx){
  int gi = blockIdx.x; int t = threadIdx.x;
  __shared__ float sv[N];
  __shared__ float rv[256]; __shared__ int ri[256];
  for (int i = t; i < N; i += 256) sv[i] = scores[gi*N + i];
  __syncthreads();
  for (int it = 0; it < KSUB; ++it){
    float bv = -INFINITY; int bi = -1;
    for (int i = t; i < N; i += 256){
      float v = sv[i];
      if (v > bv || (v == bv && bi != -1 && i < bi)) { bv = v; bi = i; }
      else if (bi == -1 && v > -INFINITY) { bv = v; bi = i; }
    }
    rv[t] = bv; ri[t] = bi;
    __syncthreads();
    #pragma unroll
    for (int s = 128; s > 0; s >>= 1){
      if (t < s){
        float ov = rv[t+s]; int oi = ri[t+s];
        if (oi != -1 && (ov > rv[t] || (ov == rv[t] && (ri[t] == -1 || oi < ri[t])))){
          rv[t]=ov; ri[t]=oi;
        }
      }
      __syncthreads();
    }
    if (t == 0){ idx[gi*KSUB + it] = ri[0]; sv[ri[0]] = -INFINITY; }
    __syncthreads();
  }
}

// ---------- 7) sub_reps[r,c] = sum_j g[idx_r,j]*rdeg[j]*hn[j,c] ----------
__global__ void k_subreps(const float* __restrict__ g, const float* __restrict__ hn,
                          const float* __restrict__ rdeg, const int* __restrict__ idx,
                          float* __restrict__ subrep){
  int gi = blockIdx.x;
  int j0 = blockIdx.y * 256;
  int wave = threadIdx.x>>6, lane = threadIdx.x&63;
  int r0 = wave * 16;
  int sidx[16];
  #pragma unroll
  for (int r = 0; r < 16; ++r) sidx[r] = idx[gi*KSUB + r0 + r];  // uniform
  const float* hb = hn + (size_t)gi*N*LD;
  const float* gb = g + (size_t)gi*NN;
  const float* rd = rdeg + gi*N;
  float acc[16];
  #pragma unroll
  for (int r = 0; r < 16; ++r) acc[r] = 0.f;
  #pragma unroll 4
  for (int jj = 0; jj < 256; ++jj){
    int j = j0 + jj;
    float hv = hb[(size_t)j*LD + lane] * rd[j];
    #pragma unroll
    for (int r = 0; r < 16; ++r)
      acc[r] = fmaf(gb[(size_t)sidx[r]*N + j], hv, acc[r]);   // scalar g broadcast
  }
  float* sb = subrep + gi*KSUB*LD;
  #pragma unroll
  for (int r = 0; r < 16; ++r) atomicAdd(&sb[(r0+r)*LD + lane], acc[r]);
}

// ---------- 8) ops -> conv(k=2) -> relu -> maxpool -> alpha mix ----------
__global__ void __launch_bounds__(192) k_head(
    const float* __restrict__ subrep, const float* __restrict__ colsum,
    const float* __restrict__ ck, const float* __restrict__ cb,
    const float* __restrict__ logal, float* __restrict__ Bm){
  int gi = blockIdx.x;
  int o  = threadIdx.x / 64;     // op index = wave (uniform per wave)
  int kk = threadIdx.x & 63;     // conv position; 0..62 valid
  __shared__ float sub[KSUB][LD+1];
  __shared__ float gm[LD];
  __shared__ float fl[3][LD];
  for (int f = threadIdx.x; f < KSUB*LD; f += 192) sub[f>>6][f&63] = subrep[gi*KSUB*LD + f];
  if (threadIdx.x < LD) gm[threadIdx.x] = colsum[gi*LD + threadIdx.x] * (1.0f/(float)N);
  __syncthreads();
  float acc[LD];
  #pragma unroll
  for (int d = 0; d < LD; ++d) acc[d] = 0.f;
  int kb = kk < 63 ? kk+1 : 63;
  for (int l = 0; l < LD; ++l){
    float s0 = sub[kk][l], s1 = sub[kb][l];
    float v0, v1;
    if (o == 0){ v0 = s0; v1 = s1; }
    else if (o == 1){ v0 = eluf(s0); v1 = eluf(s1); }
    else { v0 = s0 + gm[l]; v1 = s1 + gm[l]; }
    const float* c0 = ck + l*LD;            // uniform -> s_load
    const float* c1 = ck + LD*LD + l*LD;
    #pragma unroll
    for (int d = 0; d < LD; ++d) acc[d] = fmaf(v0, c0[d], fmaf(v1, c1[d], acc[d]));
  }
  #pragma unroll
  for (int d = 0; d < LD; ++d){
    float r = acc[d] + cb[d];
    r = (kk < 63) ? fmaxf(r, 0.f) : 0.f;    // relu; dummy lane contributes 0 (safe: relu>=0)
    #pragma unroll
    for (int off = 32; off > 0; off >>= 1) r = fmaxf(r, __shfl_xor(r, off, 64));
    if (kk == 0) fl[o][d] = r;
  }
  __syncthreads();
  if (threadIdx.x < LD){
    int d = threadIdx.x;
    float l0 = logal[0], l1 = logal[1], l2 = logal[2];
    float mx = fmaxf(l0, fmaxf(l1, l2));
    float e0 = expf(l0-mx), e1 = expf(l1-mx), e2 = expf(l2-mx);
    float inv = 1.0f/(e0+e1+e2);
    Bm[gi*LD + d] = (e0*fl[0][d] + e1*fl[1][d] + e2*fl[2][d]) * inv;
  }
}

// ---------- 9) discriminator logits ----------
__global__ void k_final(const float* __restrict__ orig, const float* __restrict__ Wd,
                        const float* __restrict__ Bm, float* __restrict__ out){
  int lane = threadIdx.x & 63;
  float wd[64];
  #pragma unroll
  for (int l = 0; l < 64; ++l) wd[l] = Wd[l*64 + lane];
  for (int i = 0; i < G; ++i){
    float wc = 0.f;
    #pragma unroll
    for (int l = 0; l < 64; ++l) wc = fmaf(orig[i*64 + l], wd[l], wc);
    float d1 = waveReduceSum(Bm[i*64 + lane] * wc);
    float d2 = waveReduceSum(Bm[((i+G-1)%G)*64 + lane] * wc);  // shuf = roll(B,1)
    if (lane == 0){ out[i] = d1; out[G + i] = d2; }
  }
}

extern "C" void kernel_launch(void* const* d_in, const int* in_sizes, int n_in,
                              void* d_out, int out_size, void* d_ws, size_t ws_size,
                              hipStream_t stream){
  const float* orig = (const float*)d_in[0];
  const float* x    = (const float*)d_in[1];
  const float* g    = (const float*)d_in[2];
  const float* Wg   = (const float*)d_in[3];
  const float* bg   = (const float*)d_in[4];
  const float* ps   = (const float*)d_in[5];
  const float* ck   = (const float*)d_in[6];
  const float* cb   = (const float*)d_in[7];
  const float* Wd   = (const float*)d_in[8];
  const float* la   = (const float*)d_in[9];
  float* out = (float*)d_out;
  float* ws  = (float*)d_ws;

  float* xwn    = ws;                        // G*N*LD
  float* hn     = xwn + (size_t)G*N*LD;      // G*N*LD
  float* rdeg   = hn + (size_t)G*N*LD;       // G*N
  float* scores = rdeg + G*N;                // G*N
  float* stats  = scores + G*N;              // 2G   --- zeroed region start
  float* colsum = stats + 2*G;               // G*LD
  float* subrep = colsum + G*LD;             // G*KSUB*LD --- zeroed region end
  float* muA    = subrep + (size_t)G*KSUB*LD;// G
  float* rsA    = muA + G;                   // G
  float* Bm     = rsA + G;                   // G*LD
  int*   idx    = (int*)(Bm + G*LD);         // G*KSUB

  hipMemsetAsync(stats, 0, (size_t)(2*G + G*LD + G*KSUB*LD)*sizeof(float), stream);
  k_deg   <<<G*N/4, 256, 0, stream>>>(g, rdeg);
  k_xw    <<<dim3(G,8), 256, 0, stream>>>(x, Wg, rdeg, xwn);
  k_mm    <<<dim3(G,8), 256, 0, stream>>>(g, xwn, bg, hn, stats);
  k_stats <<<1, 64, 0, stream>>>(stats, muA, rsA);
  k_score <<<dim3(G,8), 256, 0, stream>>>(hn, ps, muA, rsA, scores, colsum);
  k_topk  <<<G, 256, 0, stream>>>(scores, idx);
  k_subreps<<<dim3(G,8), 256, 0, stream>>>(g, hn, rdeg, idx, subrep);
  k_head  <<<G, 192, 0, stream>>>(subrep, colsum, ck, cb, la, Bm);
  k_final <<<1, 64, 0, stream>>>(orig, Wd, Bm, out);
}

// Round 2
// 1469.562 us; speedup vs baseline: 1.5122x; 1.5122x over previous
//
#include <hip/hip_runtime.h>
#include <math.h>

#define G    32
#define N    2048
#define IND  128
#define LD   64
#define KSUB 64
#define NN   ((size_t)N*(size_t)N)

__device__ __forceinline__ float eluf(float x){ return x > 0.f ? x : expm1f(x); }

__device__ __forceinline__ float waveReduceSum(float v){
  #pragma unroll
  for (int o = 32; o > 0; o >>= 1) v += __shfl_xor(v, o, 64);
  return v;
}

// ---------- 1) row degrees -> reciprocal ----------
__global__ void k_deg(const float* __restrict__ g, float* __restrict__ rdeg){
  int wave = threadIdx.x >> 6, lane = threadIdx.x & 63;
  int row = blockIdx.x * 4 + wave;              // 0 .. G*N-1
  const float* gr = g + (size_t)row * N;
  float s = 0.f;
  #pragma unroll
  for (int it = 0; it < 8; ++it){
    float4 v = *(const float4*)(gr + it*256 + lane*4);
    s += v.x + v.y + v.z + v.w;
  }
  s = waveReduceSum(s);
  if (lane == 0) rdeg[row] = 1.0f / s;
}

// ---------- 2) xwn[g,j,c] = (x[g,j,:] @ W)[c] * rdeg[g,j] ----------
// 256 thr: 16 rowgroups x 16 colgroups; R=8 rows, C=4 cols per thread.
// W (128x64 = 32KB) staged whole in LDS.
__global__ void __launch_bounds__(256, 4) k_xw(
    const float* __restrict__ x, const float* __restrict__ Wg,
    const float* __restrict__ rdeg, float* __restrict__ xwn){
  int gi = blockIdx.x;
  int rowbase = blockIdx.y * 128;
  int t = threadIdx.x;
  int rg = t >> 4, cg = t & 15;
  int c0 = cg * 4;
  __shared__ float Ws[IND][LD];     // 32 KB
  #pragma unroll
  for (int i = 0; i < 8; ++i)
    ((float4*)&Ws[0][0])[t + i*256] = ((const float4*)Wg)[t + i*256];
  __syncthreads();
  const float* xr0 = x + ((size_t)gi*N + rowbase + rg*8) * IND;
  float acc[8][4];
  #pragma unroll
  for (int r = 0; r < 8; ++r)
    #pragma unroll
    for (int c = 0; c < 4; ++c) acc[r][c] = 0.f;
  for (int k4 = 0; k4 < IND; k4 += 4){
    float4 a4[8];
    #pragma unroll
    for (int r = 0; r < 8; ++r) a4[r] = *(const float4*)(xr0 + (size_t)r*IND + k4);
    #pragma unroll
    for (int kk = 0; kk < 4; ++kk){
      float4 bv = *(const float4*)&Ws[k4+kk][c0];
      #pragma unroll
      for (int r = 0; r < 8; ++r){
        float a = ((const float*)&a4[r])[kk];
        acc[r][0] = fmaf(a, bv.x, acc[r][0]);
        acc[r][1] = fmaf(a, bv.y, acc[r][1]);
        acc[r][2] = fmaf(a, bv.z, acc[r][2]);
        acc[r][3] = fmaf(a, bv.w, acc[r][3]);
      }
    }
  }
  #pragma unroll
  for (int r = 0; r < 8; ++r){
    int row = rowbase + rg*8 + r;
    float rd = rdeg[gi*N + row];
    float4 v; v.x=acc[r][0]*rd; v.y=acc[r][1]*rd; v.z=acc[r][2]*rd; v.w=acc[r][3]*rd;
    *(float4*)(xwn + ((size_t)gi*N + row)*LD + c0) = v;
  }
}

// ---------- 3) hn = elu(g @ xwn + b); accumulate LN stats ----------
// Grid (G,16): 512 blocks of 256 thr -> 4 blocks/CU, 4 waves/SIMD.
// Tile: 128 rows x 64 cols; per-thread micro-tile R=8 x C=4.
// B k-tile (64x64=16KB) in LDS; 1 ds_read_b128 feeds 32 FMAs.
__global__ void __launch_bounds__(256, 4) k_mm(
    const float* __restrict__ g, const float* __restrict__ xwn,
    const float* __restrict__ bgcn, float* __restrict__ hn,
    float* __restrict__ stats){
  int gi = blockIdx.x;
  int rowbase = blockIdx.y * 128;
  int t = threadIdx.x;
  int rg = t >> 4, cg = t & 15;
  int c0 = cg * 4;
  __shared__ float Bs[64][LD];      // 16 KB
  __shared__ float red[8];
  const float* ar0 = g + (size_t)gi*NN + (size_t)(rowbase + rg*8) * N;
  const float* B   = xwn + (size_t)gi*N*LD;
  float acc[8][4];
  #pragma unroll
  for (int r = 0; r < 8; ++r)
    #pragma unroll
    for (int c = 0; c < 4; ++c) acc[r][c] = 0.f;

  for (int kt = 0; kt < N; kt += 64){
    __syncthreads();                               // previous tile fully read
    const float4* src = (const float4*)(B + (size_t)kt*LD);
    #pragma unroll
    for (int i = 0; i < 4; ++i)
      ((float4*)&Bs[0][0])[t + i*256] = src[t + i*256];
    __syncthreads();                               // tile visible
    for (int k4 = 0; k4 < 64; k4 += 4){
      float4 a4[8];
      #pragma unroll
      for (int r = 0; r < 8; ++r) a4[r] = *(const float4*)(ar0 + (size_t)r*N + kt + k4);
      #pragma unroll
      for (int kk = 0; kk < 4; ++kk){
        float4 bv = *(const float4*)&Bs[k4+kk][c0];
        #pragma unroll
        for (int r = 0; r < 8; ++r){
          float a = ((const float*)&a4[r])[kk];
          acc[r][0] = fmaf(a, bv.x, acc[r][0]);
          acc[r][1] = fmaf(a, bv.y, acc[r][1]);
          acc[r][2] = fmaf(a, bv.z, acc[r][2]);
          acc[r][3] = fmaf(a, bv.w, acc[r][3]);
        }
      }
    }
  }

  float4 bb = *(const float4*)(bgcn + c0);
  float s1 = 0.f, s2 = 0.f;
  #pragma unroll
  for (int r = 0; r < 8; ++r){
    int row = rowbase + rg*8 + r;
    float4 v;
    v.x = eluf(acc[r][0] + bb.x);
    v.y = eluf(acc[r][1] + bb.y);
    v.z = eluf(acc[r][2] + bb.z);
    v.w = eluf(acc[r][3] + bb.w);
    s1 += v.x+v.y+v.z+v.w;
    s2 += v.x*v.x + v.y*v.y + v.z*v.z + v.w*v.w;
    *(float4*)(hn + ((size_t)gi*N + row)*LD + c0) = v;
  }
  s1 = waveReduceSum(s1); s2 = waveReduceSum(s2);
  int wave = t >> 6, lane = t & 63;
  if (lane == 0){ red[wave] = s1; red[4+wave] = s2; }
  __syncthreads();
  if (t == 0){
    atomicAdd(&stats[gi*2+0], red[0]+red[1]+red[2]+red[3]);
    atomicAdd(&stats[gi*2+1], red[4]+red[5]+red[6]+red[7]);
  }
}

// ---------- 4) finalize LN stats ----------
__global__ void k_stats(const float* __restrict__ stats, float* __restrict__ mu,
                        float* __restrict__ rs){
  int t = threadIdx.x;
  if (t < G){
    const float inv = 1.0f/(float)(N*LD);
    float m = stats[2*t]*inv;
    float v = stats[2*t+1]*inv - m*m;
    mu[t] = m; rs[t] = rsqrtf(v + 1e-5f);
  }
}

// ---------- 5) normalize in-place, scores, column sums ----------
__global__ void k_score(float* __restrict__ hn, const float* __restrict__ p,
                        const float* __restrict__ muA, const float* __restrict__ rsA,
                        float* __restrict__ scores, float* __restrict__ colsum){
  int gi = blockIdx.x;
  int wave = threadIdx.x>>6, lane = threadIdx.x&63;
  int rbase = blockIdx.y*256 + wave*64;
  float mu = muA[gi], rs = rsA[gi], pl = p[lane];
  float cs = 0.f;
  for (int r = 0; r < 64; ++r){
    int row = rbase + r;
    float* hp = hn + ((size_t)gi*N + row)*LD + lane;
    float v = (*hp - mu) * rs;
    *hp = v;
    cs += v;
    float sv = waveReduceSum(v * pl);
    if (lane == 0) scores[gi*N + row] = sv;
  }
  atomicAdd(&colsum[gi*LD + lane], cs);
}

// ---------- 6) exact top-64 (desc value, asc index on ties) ----------
__global__ void k_topk(const float* __restrict__ scores, int* __restrict__ idx){
  int gi = blockIdx.x; int t = threadIdx.x;
  __shared__ float sv[N];
  __shared__ float rv[256]; __shared__ int ri[256];
  for (int i = t; i < N; i += 256) sv[i] = scores[gi*N + i];
  __syncthreads();
  for (int it = 0; it < KSUB; ++it){
    float bv = -INFINITY; int bi = -1;
    for (int i = t; i < N; i += 256){
      float v = sv[i];
      if (v > bv || (v == bv && bi != -1 && i < bi)) { bv = v; bi = i; }
      else if (bi == -1 && v > -INFINITY) { bv = v; bi = i; }
    }
    rv[t] = bv; ri[t] = bi;
    __syncthreads();
    #pragma unroll
    for (int s = 128; s > 0; s >>= 1){
      if (t < s){
        float ov = rv[t+s]; int oi = ri[t+s];
        if (oi != -1 && (ov > rv[t] || (ov == rv[t] && (ri[t] == -1 || oi < ri[t])))){
          rv[t]=ov; ri[t]=oi;
        }
      }
      __syncthreads();
    }
    if (t == 0){ idx[gi*KSUB + it] = ri[0]; sv[ri[0]] = -INFINITY; }
    __syncthreads();
  }
}

// ---------- 7) sub_reps[r,c] = sum_j g[idx_r,j]*rdeg[j]*hn[j,c] ----------
__global__ void k_subreps(const float* __restrict__ g, const float* __restrict__ hn,
                          const float* __restrict__ rdeg, const int* __restrict__ idx,
                          float* __restrict__ subrep){
  int gi = blockIdx.x;
  int j0 = blockIdx.y * 256;
  int wave = threadIdx.x>>6, lane = threadIdx.x&63;
  int r0 = wave * 16;
  int sidx[16];
  #pragma unroll
  for (int r = 0; r < 16; ++r) sidx[r] = idx[gi*KSUB + r0 + r];  // uniform
  const float* hb = hn + (size_t)gi*N*LD;
  const float* gb = g + (size_t)gi*NN;
  const float* rd = rdeg + gi*N;
  float acc[16];
  #pragma unroll
  for (int r = 0; r < 16; ++r) acc[r] = 0.f;
  #pragma unroll 4
  for (int jj = 0; jj < 256; ++jj){
    int j = j0 + jj;
    float hv = hb[(size_t)j*LD + lane] * rd[j];
    #pragma unroll
    for (int r = 0; r < 16; ++r)
      acc[r] = fmaf(gb[(size_t)sidx[r]*N + j], hv, acc[r]);   // scalar g broadcast
  }
  float* sb = subrep + gi*KSUB*LD;
  #pragma unroll
  for (int r = 0; r < 16; ++r) atomicAdd(&sb[(r0+r)*LD + lane], acc[r]);
}

// ---------- 8) ops -> conv(k=2) -> relu -> maxpool -> alpha mix ----------
__global__ void __launch_bounds__(192) k_head(
    const float* __restrict__ subrep, const float* __restrict__ colsum,
    const float* __restrict__ ck, const float* __restrict__ cb,
    const float* __restrict__ logal, float* __restrict__ Bm){
  int gi = blockIdx.x;
  int o  = threadIdx.x / 64;     // op index = wave (uniform per wave)
  int kk = threadIdx.x & 63;     // conv position; 0..62 valid
  __shared__ float sub[KSUB][LD+1];
  __shared__ float gm[LD];
  __shared__ float fl[3][LD];
  for (int f = threadIdx.x; f < KSUB*LD; f += 192) sub[f>>6][f&63] = subrep[gi*KSUB*LD + f];
  if (threadIdx.x < LD) gm[threadIdx.x] = colsum[gi*LD + threadIdx.x] * (1.0f/(float)N);
  __syncthreads();
  float acc[LD];
  #pragma unroll
  for (int d = 0; d < LD; ++d) acc[d] = 0.f;
  int kb = kk < 63 ? kk+1 : 63;
  for (int l = 0; l < LD; ++l){
    float s0 = sub[kk][l], s1 = sub[kb][l];
    float v0, v1;
    if (o == 0){ v0 = s0; v1 = s1; }
    else if (o == 1){ v0 = eluf(s0); v1 = eluf(s1); }
    else { v0 = s0 + gm[l]; v1 = s1 + gm[l]; }
    const float* c0 = ck + l*LD;            // uniform -> s_load
    const float* c1 = ck + LD*LD + l*LD;
    #pragma unroll
    for (int d = 0; d < LD; ++d) acc[d] = fmaf(v0, c0[d], fmaf(v1, c1[d], acc[d]));
  }
  #pragma unroll
  for (int d = 0; d < LD; ++d){
    float r = acc[d] + cb[d];
    r = (kk < 63) ? fmaxf(r, 0.f) : 0.f;    // relu; dummy lane contributes 0 (safe: relu>=0)
    #pragma unroll
    for (int off = 32; off > 0; off >>= 1) r = fmaxf(r, __shfl_xor(r, off, 64));
    if (kk == 0) fl[o][d] = r;
  }
  __syncthreads();
  if (threadIdx.x < LD){
    int d = threadIdx.x;
    float l0 = logal[0], l1 = logal[1], l2 = logal[2];
    float mx = fmaxf(l0, fmaxf(l1, l2));
    float e0 = expf(l0-mx), e1 = expf(l1-mx), e2 = expf(l2-mx);
    float inv = 1.0f/(e0+e1+e2);
    Bm[gi*LD + d] = (e0*fl[0][d] + e1*fl[1][d] + e2*fl[2][d]) * inv;
  }
}

// ---------- 9) discriminator logits ----------
__global__ void k_final(const float* __restrict__ orig, const float* __restrict__ Wd,
                        const float* __restrict__ Bm, float* __restrict__ out){
  int lane = threadIdx.x & 63;
  float wd[64];
  #pragma unroll
  for (int l = 0; l < 64; ++l) wd[l] = Wd[l*64 + lane];
  for (int i = 0; i < G; ++i){
    float wc = 0.f;
    #pragma unroll
    for (int l = 0; l < 64; ++l) wc = fmaf(orig[i*64 + l], wd[l], wc);
    float d1 = waveReduceSum(Bm[i*64 + lane] * wc);
    float d2 = waveReduceSum(Bm[((i+G-1)%G)*64 + lane] * wc);  // shuf = roll(B,1)
    if (lane == 0){ out[i] = d1; out[G + i] = d2; }
  }
}

extern "C" void kernel_launch(void* const* d_in, const int* in_sizes, int n_in,
                              void* d_out, int out_size, void* d_ws, size_t ws_size,
                              hipStream_t stream){
  const float* orig = (const float*)d_in[0];
  const float* x    = (const float*)d_in[1];
  const float* g    = (const float*)d_in[2];
  const float* Wg   = (const float*)d_in[3];
  const float* bg   = (const float*)d_in[4];
  const float* ps   = (const float*)d_in[5];
  const float* ck   = (const float*)d_in[6];
  const float* cb   = (const float*)d_in[7];
  const float* Wd   = (const float*)d_in[8];
  const float* la   = (const float*)d_in[9];
  float* out = (float*)d_out;
  float* ws  = (float*)d_ws;

  float* xwn    = ws;                        // G*N*LD
  float* hn     = xwn + (size_t)G*N*LD;      // G*N*LD
  float* rdeg   = hn + (size_t)G*N*LD;       // G*N
  float* scores = rdeg + G*N;                // G*N
  float* stats  = scores + G*N;              // 2G   --- zeroed region start
  float* colsum = stats + 2*G;               // G*LD
  float* subrep = colsum + G*LD;             // G*KSUB*LD --- zeroed region end
  float* muA    = subrep + (size_t)G*KSUB*LD;// G
  float* rsA    = muA + G;                   // G
  float* Bm     = rsA + G;                   // G*LD
  int*   idx    = (int*)(Bm + G*LD);         // G*KSUB

  hipMemsetAsync(stats, 0, (size_t)(2*G + G*LD + G*KSUB*LD)*sizeof(float), stream);
  k_deg   <<<G*N/4, 256, 0, stream>>>(g, rdeg);
  k_xw    <<<dim3(G,16), 256, 0, stream>>>(x, Wg, rdeg, xwn);
  k_mm    <<<dim3(G,16), 256, 0, stream>>>(g, xwn, bg, hn, stats);
  k_stats <<<1, 64, 0, stream>>>(stats, muA, rsA);
  k_score <<<dim3(G,8), 256, 0, stream>>>(hn, ps, muA, rsA, scores, colsum);
  k_topk  <<<G, 256, 0, stream>>>(scores, idx);
  k_subreps<<<dim3(G,8), 256, 0, stream>>>(g, hn, rdeg, idx, subrep);
  k_head  <<<G, 192, 0, stream>>>(subrep, colsum, ck, cb, la, Bm);
  k_final <<<1, 64, 0, stream>>>(orig, Wd, Bm, out);
}